// Round 18
// baseline (155.987 us; speedup 1.0000x reference)
//
#include <hip/hip_runtime.h>
#include <hip/hip_bf16.h>

typedef __attribute__((ext_vector_type(8))) short bf16x8;
typedef __attribute__((ext_vector_type(4))) float f32x4;

#define SEQ  2048
#define NH   16
#define DH   64

__device__ __forceinline__ unsigned short f2bf(float f) {
  union { float f; unsigned int u; } v; v.f = f;
  unsigned int r = v.u + 0x7FFFu + ((v.u >> 16) & 1u);
  return (unsigned short)(r >> 16);
}

__device__ __forceinline__ unsigned int cvt_pk_bf16(float a, float b) {
  unsigned int r;
  asm("v_cvt_pk_bf16_f32 %0, %1, %2" : "=v"(r) : "v"(a), "v"(b));
  return r;
}

__device__ __forceinline__ void load_lds16(const void* g, void* l) {
  __builtin_amdgcn_global_load_lds(
      (const __attribute__((address_space(1))) unsigned int*)g,
      (__attribute__((address_space(3))) unsigned int*)l, 16, 0, 0);
}

// ---------------- LayerNorm + cast to bf16 (R17 verbatim) ----------------
__global__ __launch_bounds__(256) void ln_cast_kernel(
    const float* __restrict__ x, const float* __restrict__ gg,
    const float* __restrict__ bb, unsigned short* __restrict__ xn) {
  int row = blockIdx.x;                     // 0..4095
  int t = threadIdx.x;                      // 0..255, 4 floats each
  const float* xr = x + (size_t)row * 1024;
  float4 v = ((const float4*)xr)[t];
  float s  = v.x + v.y + v.z + v.w;
  float ss = v.x*v.x + v.y*v.y + v.z*v.z + v.w*v.w;
  #pragma unroll
  for (int m = 1; m < 64; m <<= 1) {
    s  += __shfl_xor(s, m);
    ss += __shfl_xor(ss, m);
  }
  __shared__ float red[8];
  int wave = t >> 6;
  if ((t & 63) == 0) { red[wave] = s; red[wave + 4] = ss; }
  __syncthreads();
  s  = red[0] + red[1] + red[2] + red[3];
  ss = red[4] + red[5] + red[6] + red[7];
  float mu  = s * (1.0f / 1024.0f);
  float var = ss * (1.0f / 1024.0f) - mu * mu;
  float rstd = rsqrtf(var + 1e-5f);
  float4 g4 = ((const float4*)gg)[t];
  float4 b4 = ((const float4*)bb)[t];
  ushort4 o;
  o.x = f2bf((v.x - mu) * rstd * g4.x + b4.x);
  o.y = f2bf((v.y - mu) * rstd * g4.y + b4.y);
  o.z = f2bf((v.z - mu) * rstd * g4.z + b4.z);
  o.w = f2bf((v.w - mu) * rstd * g4.w + b4.w);
  ((ushort4*)(xn + (size_t)row * 1024))[t] = o;
}

// ---------------- transpose + cast: w[K][Nn] fp32 -> wt[Nn][K] bf16 ----------------
__global__ __launch_bounds__(256) void transpose_cast_kernel(
    const float* __restrict__ w, unsigned short* __restrict__ wt,
    int K, int Nn) {
  __shared__ unsigned short tile[64][68];
  int k0 = blockIdx.y * 64;
  int n0 = blockIdx.x * 64;
  int t = threadIdx.x;
  int tr = t >> 4;            // 0..15
  int tc = (t & 15) * 4;      // 0..60
  #pragma unroll
  for (int it = 0; it < 4; ++it) {
    int r = tr + it * 16;
    float4 v = *(const float4*)(w + (size_t)(k0 + r) * Nn + n0 + tc);
    tile[r][tc + 0] = f2bf(v.x);
    tile[r][tc + 1] = f2bf(v.y);
    tile[r][tc + 2] = f2bf(v.z);
    tile[r][tc + 3] = f2bf(v.w);
  }
  __syncthreads();
  #pragma unroll
  for (int it = 0; it < 4; ++it) {
    int nr = tr + it * 16;
    ushort4 o;
    o.x = tile[tc + 0][nr];
    o.y = tile[tc + 1][nr];
    o.z = tile[tc + 2][nr];
    o.w = tile[tc + 3][nr];
    *(ushort4*)(wt + (size_t)(n0 + nr) * K + k0 + tc) = o;
  }
}

// ---------------- GEMM: C[M x TN-tile] = A[M][1024] * Bt[Nn][1024]^T + bias --------
// R17 template verbatim. Both instantiations now TN=64: gemm<0> grid 1536
// blocks (~6/CU) so the per-K-step barrier drain is hidden by co-resident
// blocks; per-(m,n) accumulation order and epilogue expressions unchanged ->
// bit-exact per output element (only block ownership of columns moves).
template<int MODE, int TN>
__global__ __launch_bounds__(256) void gemm_kernel(
    const unsigned short* __restrict__ A,
    const unsigned short* __restrict__ Bt,
    const float* __restrict__ bias,
    float* __restrict__ outF,
    unsigned short* __restrict__ qw,
    unsigned short* __restrict__ kw,
    unsigned short* __restrict__ vt)
{
  constexpr int K = 1024;
  constexpr int NI = TN / 32;            // B-frag repeats per wave (4 or 2)
  __shared__ __align__(16) unsigned short As[2][128 * 32];
  __shared__ __align__(16) unsigned short Bs[2][TN * 32];
  int tid = threadIdx.x;
  int wave = tid >> 6, lane = tid & 63;
  int col = lane & 15, g = lane >> 4;

  // XCD-chunked swizzle (bijective since nwg % 8 == 0)
  int nwg = gridDim.x * gridDim.y;
  int bid = blockIdx.y * gridDim.x + blockIdx.x;
  int wg = (bid & 7) * (nwg >> 3) + (bid >> 3);
  int n0 = (wg % gridDim.x) * TN;
  int m0 = (wg / gridDim.x) * 128;

  int wm = (wave >> 1) * 64, wn = (wave & 1) * (TN / 2);
  int r0 = tid >> 2, ch = (tid & 3) * 8;

  f32x4 acc[4][NI] = {};

  const unsigned short* ga = A  + (size_t)(m0 + r0) * K + ch;
  const unsigned short* gb = Bt + (size_t)(n0 + r0) * K + ch;
  int lofs = wave * 512;

  // prologue: stage K-step 0 into buffer 0
  load_lds16(ga,                  &As[0][lofs]);
  load_lds16(ga + (size_t)64 * K, &As[0][2048 + lofs]);
  load_lds16(gb,                  &Bs[0][lofs]);
  if (TN == 128)
    load_lds16(gb + (size_t)64 * K, &Bs[0][2048 + lofs]);

  for (int t = 0; t < K / 32; ++t) {
    int cur = t & 1, nxt = cur ^ 1;
    __syncthreads();   // stage(t) landed (vmcnt drain); buf[nxt] free

    if (t + 1 < K / 32) {
      int ktn = (t + 1) * 32;
      load_lds16(ga + ktn,                  &As[nxt][lofs]);
      load_lds16(ga + (size_t)64 * K + ktn, &As[nxt][2048 + lofs]);
      load_lds16(gb + ktn,                  &Bs[nxt][lofs]);
      if (TN == 128)
        load_lds16(gb + (size_t)64 * K + ktn, &Bs[nxt][2048 + lofs]);
    }

    bf16x8 af[4], bfr[NI];
    #pragma unroll
    for (int i = 0; i < 4; ++i)
      af[i] = *(const bf16x8*)&As[cur][(wm + i * 16 + col) * 32 + g * 8];
    #pragma unroll
    for (int i = 0; i < NI; ++i)
      bfr[i] = *(const bf16x8*)&Bs[cur][(wn + i * 16 + col) * 32 + g * 8];
    #pragma unroll
    for (int mi = 0; mi < 4; ++mi)
      #pragma unroll
      for (int ni = 0; ni < NI; ++ni)
        acc[mi][ni] = __builtin_amdgcn_mfma_f32_16x16x32_bf16(
            af[mi], bfr[ni], acc[mi][ni], 0, 0, 0);
  }

  if (MODE == 0) {
    #pragma unroll
    for (int ni = 0; ni < NI; ++ni) {
      int n = n0 + wn + ni * 16 + col;
      float bv = bias[n];
      int t3 = n >> 10;
      int within = n & 1023;
      int h = within >> 6, d = within & 63;
      if (t3 == 2) {
        // V: PV-fragment-packed store
        #pragma unroll
        for (int mi = 0; mi < 4; ++mi) {
          int mb = m0 + wm + mi * 16 + g * 4;
          int b = mb >> 11, tok = mb & 2047;
          int kt32 = tok >> 5;
          int pair = mi & 1;
          ushort4 o;
          o.x = f2bf(acc[mi][ni][0] + bv);
          o.y = f2bf(acc[mi][ni][1] + bv);
          o.z = f2bf(acc[mi][ni][2] + bv);
          o.w = f2bf(acc[mi][ni][3] + bv);
          *(ushort4*)&vt[(((size_t)(b * NH + h) * (SEQ / 32) + kt32) * DH + d) * 32
                         + g * 8 + pair * 4] = o;
        }
      } else {
        unsigned short* dst = (t3 == 0) ? qw : kw;
        float scl = (t3 == 0) ? 0.125f : 1.0f;
        #pragma unroll
        for (int mi = 0; mi < 4; ++mi) {
          int mb = m0 + wm + mi * 16 + g * 4;
          #pragma unroll
          for (int j = 0; j < 4; ++j) {
            int m = mb + j;
            int b = m >> 11, tok = m & 2047;
            float val = (acc[mi][ni][j] + bv) * scl;
            dst[(((size_t)(b * NH + h) * SEQ + tok) << 6) + d] = f2bf(val);
          }
        }
      }
    }
  } else {
    #pragma unroll
    for (int ni = 0; ni < NI; ++ni) {
      int n = n0 + wn + ni * 16 + col;
      float bv = bias[n];
      #pragma unroll
      for (int mi = 0; mi < 4; ++mi) {
        int mb = m0 + wm + mi * 16 + g * 4;
        #pragma unroll
        for (int j = 0; j < 4; ++j)
          outF[(size_t)(mb + j) * 1024 + n] = acc[mi][ni][j] + bv;
      }
    }
  }
}

// ---------------- flash attention, LDS double-buffered DMA pipeline ----------------
// BYTE-IDENTICAL to R17 (passing, absmax 5.95e-4). Numerics frozen.
__global__ __launch_bounds__(256, 4) void attn_kernel(
    const unsigned short* __restrict__ qg,   // [B*H][SEQ][64], pre-scaled by 0.125
    const unsigned short* __restrict__ kg,   // [B*H][SEQ][64]
    const unsigned short* __restrict__ vfg,  // [B*H][SEQ/32][64][32r]
    unsigned short* __restrict__ og)         // [B][SEQ][1024] bf16
{
  __shared__ __align__(16) unsigned short lds[2][16 * 512];  // 2 x 16KB

  int tid = threadIdx.x;
  int wave = tid >> 6, lane = tid & 63;
  int col = lane & 15, g = lane >> 4;
  int bid = blockIdx.x + (blockIdx.y << 5);      // 0..1023
  int wgid = ((bid & 7) << 7) | (bid >> 3);      // XCD-chunked, bijective
  int qtile = wgid & 31;
  int bh = wgid >> 5;
  int b = bh >> 4, h = bh & 15;
  int q0 = qtile * 64 + wave * 16;

  const unsigned short* Q  = qg  + (size_t)bh * SEQ * DH;
  const unsigned short* Kp = kg  + (size_t)bh * SEQ * DH;
  const unsigned short* VF = vfg + (size_t)bh * (SEQ / 32) * DH * 32;

  const unsigned short* qr = Q + (size_t)(q0 + col) * DH + g * 8;
  bf16x8 qf0 = *(const bf16x8*)qr;
  bf16x8 qf1 = *(const bf16x8*)(qr + 32);

  // this wave's 4 staging chunks: idx 0..7 = K(ns=idx>>1, c=idx&1),
  // idx 8..15 = V(h2=(idx-8)>>2, ds=(idx-8)&3)
  int idx0 = wave * 4;

  f32x4 oacc[4] = {};
  float mrow = -1e30f, lrow = 0.0f;

  // prologue: stage tile 0 into buf 0
  #pragma unroll
  for (int i = 0; i < 4; ++i) {
    int idx = idx0 + i;
    const unsigned short* src;
    if (idx < 8) {
      int ns = idx >> 1, c = idx & 1;
      src = Kp + (size_t)(0 + ns * 16 + col) * DH + c * 32 + g * 8;
    } else {
      int vi = idx - 8, h2 = vi >> 2, ds = vi & 3;
      src = VF + (size_t)(0 + h2) * 2048 + (ds * 16 + col) * 32 + g * 8;
    }
    load_lds16(src, &lds[0][idx * 512]);
  }

  for (int t = 0; t < SEQ / 64; ++t) {
    int cur = t & 1, nxt = cur ^ 1;
    int kt = t * 64;
    __syncthreads();   // stage(t) complete (vmcnt drain) + buf[nxt] free

    // ---- issue DMA for tile t+1 into buf[nxt] ----
    if (t + 1 < SEQ / 64) {
      int ktn = kt + 64;
      #pragma unroll
      for (int i = 0; i < 4; ++i) {
        int idx = idx0 + i;
        const unsigned short* src;
        if (idx < 8) {
          int ns = idx >> 1, c = idx & 1;
          src = Kp + (size_t)(ktn + ns * 16 + col) * DH + c * 32 + g * 8;
        } else {
          int vi = idx - 8, h2 = vi >> 2, ds = vi & 3;
          src = VF + (size_t)((ktn >> 5) + h2) * 2048 + (ds * 16 + col) * 32 + g * 8;
        }
        load_lds16(src, &lds[nxt][idx * 512]);
      }
    }

    // ---- S^T = K * Q^T from LDS fragments ----
    f32x4 s[4];
    #pragma unroll
    for (int ns = 0; ns < 4; ++ns) {
      bf16x8 kf0 = *(const bf16x8*)&lds[cur][(ns * 2 + 0) * 512 + lane * 8];
      bf16x8 kf1 = *(const bf16x8*)&lds[cur][(ns * 2 + 1) * 512 + lane * 8];
      f32x4 z = {0.f, 0.f, 0.f, 0.f};
      z = __builtin_amdgcn_mfma_f32_16x16x32_bf16(kf0, qf0, z, 0, 0, 0);
      s[ns] = __builtin_amdgcn_mfma_f32_16x16x32_bf16(kf1, qf1, z, 0, 0, 0);
    }

    // ---- online softmax (per-lane; q = q0+col) ----
    float tmax = s[0][0];
    #pragma unroll
    for (int ns = 0; ns < 4; ++ns)
      #pragma unroll
      for (int jj = 0; jj < 4; ++jj)
        tmax = fmaxf(tmax, s[ns][jj]);
    tmax = fmaxf(tmax, __shfl_xor(tmax, 16));
    tmax = fmaxf(tmax, __shfl_xor(tmax, 32));
    float mn = fmaxf(mrow, tmax);
    float corr = __expf(mrow - mn);
    mrow = mn;

    float p[4][4];
    float rs = 0.0f;
    #pragma unroll
    for (int ns = 0; ns < 4; ++ns)
      #pragma unroll
      for (int jj = 0; jj < 4; ++jj) {
        float pv = __expf(s[ns][jj] - mn);
        p[ns][jj] = pv;
        rs += pv;
      }
    rs += __shfl_xor(rs, 16);
    rs += __shfl_xor(rs, 32);
    lrow = lrow * corr + rs;
    #pragma unroll
    for (int ds = 0; ds < 4; ++ds) {
      oacc[ds][0] *= corr; oacc[ds][1] *= corr;
      oacc[ds][2] *= corr; oacc[ds][3] *= corr;
    }

    // ---- pack P to bf16 fragments ----
    union U8 { bf16x8 v; unsigned int u[4]; } pf0, pf1;
    pf0.u[0] = cvt_pk_bf16(p[0][0], p[0][1]);
    pf0.u[1] = cvt_pk_bf16(p[0][2], p[0][3]);
    pf0.u[2] = cvt_pk_bf16(p[1][0], p[1][1]);
    pf0.u[3] = cvt_pk_bf16(p[1][2], p[1][3]);
    pf1.u[0] = cvt_pk_bf16(p[2][0], p[2][1]);
    pf1.u[1] = cvt_pk_bf16(p[2][2], p[2][3]);
    pf1.u[2] = cvt_pk_bf16(p[3][0], p[3][1]);
    pf1.u[3] = cvt_pk_bf16(p[3][2], p[3][3]);

    // ---- O^T += V^T * P^T (permuted-k 16x16x32), V frags from LDS ----
    #pragma unroll
    for (int ds = 0; ds < 4; ++ds) {
      bf16x8 vfA = *(const bf16x8*)&lds[cur][(8 + ds) * 512 + lane * 8];
      oacc[ds] = __builtin_amdgcn_mfma_f32_16x16x32_bf16(vfA, pf0.v, oacc[ds], 0, 0, 0);
    }
    #pragma unroll
    for (int ds = 0; ds < 4; ++ds) {
      bf16x8 vfB = *(const bf16x8*)&lds[cur][(12 + ds) * 512 + lane * 8];
      oacc[ds] = __builtin_amdgcn_mfma_f32_16x16x32_bf16(vfB, pf1.v, oacc[ds], 0, 0, 0);
    }
  }

  // ---- normalize + store: lane owns q = q0+col, d = ds*16+g*4+jj ----
  float inv = 1.0f / lrow;
  int q = q0 + col;
  unsigned short* orow = og + (size_t)(b * SEQ + q) * 1024 + h * DH;
  #pragma unroll
  for (int ds = 0; ds < 4; ++ds) {
    ushort4 o;
    o.x = f2bf(oacc[ds][0] * inv);
    o.y = f2bf(oacc[ds][1] * inv);
    o.z = f2bf(oacc[ds][2] * inv);
    o.w = f2bf(oacc[ds][3] * inv);
    *(ushort4*)&orow[ds * 16 + g * 4] = o;
  }
}

extern "C" void kernel_launch(void* const* d_in, const int* in_sizes, int n_in,
                              void* d_out, int out_size, void* d_ws, size_t ws_size,
                              hipStream_t stream) {
  const float* x      = (const float*)d_in[0];
  const float* ln_g   = (const float*)d_in[1];
  const float* ln_b   = (const float*)d_in[2];
  const float* w_qkv  = (const float*)d_in[3];
  const float* b_qkv  = (const float*)d_in[4];
  const float* w_proj = (const float*)d_in[5];
  const float* b_proj = (const float*)d_in[6];
  float* out = (float*)d_out;

  unsigned short* ws = (unsigned short*)d_ws;
  unsigned short* xn     = ws;                       // 4096*1024
  unsigned short* wqkvT  = ws + 4194304;             // 3072*1024
  unsigned short* wprojT = wqkvT + 3145728;          // 1024*1024
  unsigned short* qw     = wprojT + 1048576;         // 32*2048*64
  unsigned short* kw     = qw + 4194304;
  unsigned short* vf     = kw + 4194304;             // packed fragments
  unsigned short* ao     = xn;                       // reuse xn after QKV GEMM

  ln_cast_kernel<<<dim3(4096), dim3(256), 0, stream>>>(x, ln_g, ln_b, xn);
  transpose_cast_kernel<<<dim3(48, 16), dim3(256), 0, stream>>>(w_qkv, wqkvT, 1024, 3072);
  transpose_cast_kernel<<<dim3(16, 16), dim3(256), 0, stream>>>(w_proj, wprojT, 1024, 1024);
  gemm_kernel<0, 64><<<dim3(48, 32), dim3(256), 0, stream>>>(
      xn, wqkvT, b_qkv, nullptr, qw, kw, vf);
  attn_kernel<<<dim3(32, 32), dim3(256), 0, stream>>>(qw, kw, vf, ao);
  gemm_kernel<1, 64><<<dim3(16, 32), dim3(256), 0, stream>>>(
      ao, wprojT, b_proj, out, nullptr, nullptr, nullptr);
}

// Round 19
// 141.687 us; speedup vs baseline: 1.1009x; 1.1009x over previous
//
#include <hip/hip_runtime.h>
#include <hip/hip_bf16.h>

typedef __attribute__((ext_vector_type(8))) short bf16x8;
typedef __attribute__((ext_vector_type(4))) float f32x4;

#define SEQ  2048
#define NH   16
#define DH   64

__device__ __forceinline__ unsigned short f2bf(float f) {
  union { float f; unsigned int u; } v; v.f = f;
  unsigned int r = v.u + 0x7FFFu + ((v.u >> 16) & 1u);
  return (unsigned short)(r >> 16);
}

__device__ __forceinline__ unsigned int cvt_pk_bf16(float a, float b) {
  unsigned int r;
  asm("v_cvt_pk_bf16_f32 %0, %1, %2" : "=v"(r) : "v"(a), "v"(b));
  return r;
}

__device__ __forceinline__ void load_lds16(const void* g, void* l) {
  __builtin_amdgcn_global_load_lds(
      (const __attribute__((address_space(1))) unsigned int*)g,
      (__attribute__((address_space(3))) unsigned int*)l, 16, 0, 0);
}

// ---------------- LayerNorm + cast to bf16 (R17 verbatim) ----------------
__global__ __launch_bounds__(256) void ln_cast_kernel(
    const float* __restrict__ x, const float* __restrict__ gg,
    const float* __restrict__ bb, unsigned short* __restrict__ xn) {
  int row = blockIdx.x;                     // 0..4095
  int t = threadIdx.x;                      // 0..255, 4 floats each
  const float* xr = x + (size_t)row * 1024;
  float4 v = ((const float4*)xr)[t];
  float s  = v.x + v.y + v.z + v.w;
  float ss = v.x*v.x + v.y*v.y + v.z*v.z + v.w*v.w;
  #pragma unroll
  for (int m = 1; m < 64; m <<= 1) {
    s  += __shfl_xor(s, m);
    ss += __shfl_xor(ss, m);
  }
  __shared__ float red[8];
  int wave = t >> 6;
  if ((t & 63) == 0) { red[wave] = s; red[wave + 4] = ss; }
  __syncthreads();
  s  = red[0] + red[1] + red[2] + red[3];
  ss = red[4] + red[5] + red[6] + red[7];
  float mu  = s * (1.0f / 1024.0f);
  float var = ss * (1.0f / 1024.0f) - mu * mu;
  float rstd = rsqrtf(var + 1e-5f);
  float4 g4 = ((const float4*)gg)[t];
  float4 b4 = ((const float4*)bb)[t];
  ushort4 o;
  o.x = f2bf((v.x - mu) * rstd * g4.x + b4.x);
  o.y = f2bf((v.y - mu) * rstd * g4.y + b4.y);
  o.z = f2bf((v.z - mu) * rstd * g4.z + b4.z);
  o.w = f2bf((v.w - mu) * rstd * g4.w + b4.w);
  ((ushort4*)(xn + (size_t)row * 1024))[t] = o;
}

// ---------------- transpose + cast: w[K][Nn] fp32 -> wt[Nn][K] bf16 ----------------
__global__ __launch_bounds__(256) void transpose_cast_kernel(
    const float* __restrict__ w, unsigned short* __restrict__ wt,
    int K, int Nn) {
  __shared__ unsigned short tile[64][68];
  int k0 = blockIdx.y * 64;
  int n0 = blockIdx.x * 64;
  int t = threadIdx.x;
  int tr = t >> 4;            // 0..15
  int tc = (t & 15) * 4;      // 0..60
  #pragma unroll
  for (int it = 0; it < 4; ++it) {
    int r = tr + it * 16;
    float4 v = *(const float4*)(w + (size_t)(k0 + r) * Nn + n0 + tc);
    tile[r][tc + 0] = f2bf(v.x);
    tile[r][tc + 1] = f2bf(v.y);
    tile[r][tc + 2] = f2bf(v.z);
    tile[r][tc + 3] = f2bf(v.w);
  }
  __syncthreads();
  #pragma unroll
  for (int it = 0; it < 4; ++it) {
    int nr = tr + it * 16;
    ushort4 o;
    o.x = tile[tc + 0][nr];
    o.y = tile[tc + 1][nr];
    o.z = tile[tc + 2][nr];
    o.w = tile[tc + 3][nr];
    *(ushort4*)(wt + (size_t)(n0 + nr) * K + k0 + tc) = o;
  }
}

// ---------------- GEMM: C[M x TN-tile] = A[M][1024] * Bt[Nn][1024]^T + bias --------
// R17 configuration (the session best): gemm<0> TN=128 (3 blocks/CU, fat tile
// keeps A-side L2 traffic low), gemm<1> TN=64 (2 blocks/CU hides the barrier
// drain that a 1-block/CU launch fully exposes — R18 showed TN=64 on gemm<0>
// regresses: it doubles A-traffic when occupancy was already sufficient).
template<int MODE, int TN>
__global__ __launch_bounds__(256) void gemm_kernel(
    const unsigned short* __restrict__ A,
    const unsigned short* __restrict__ Bt,
    const float* __restrict__ bias,
    float* __restrict__ outF,
    unsigned short* __restrict__ qw,
    unsigned short* __restrict__ kw,
    unsigned short* __restrict__ vt)
{
  constexpr int K = 1024;
  constexpr int NI = TN / 32;            // B-frag repeats per wave (4 or 2)
  __shared__ __align__(16) unsigned short As[2][128 * 32];
  __shared__ __align__(16) unsigned short Bs[2][TN * 32];
  int tid = threadIdx.x;
  int wave = tid >> 6, lane = tid & 63;
  int col = lane & 15, g = lane >> 4;

  // XCD-chunked swizzle (bijective since nwg % 8 == 0)
  int nwg = gridDim.x * gridDim.y;
  int bid = blockIdx.y * gridDim.x + blockIdx.x;
  int wg = (bid & 7) * (nwg >> 3) + (bid >> 3);
  int n0 = (wg % gridDim.x) * TN;
  int m0 = (wg / gridDim.x) * 128;

  int wm = (wave >> 1) * 64, wn = (wave & 1) * (TN / 2);
  int r0 = tid >> 2, ch = (tid & 3) * 8;

  f32x4 acc[4][NI] = {};

  const unsigned short* ga = A  + (size_t)(m0 + r0) * K + ch;
  const unsigned short* gb = Bt + (size_t)(n0 + r0) * K + ch;
  int lofs = wave * 512;

  // prologue: stage K-step 0 into buffer 0
  load_lds16(ga,                  &As[0][lofs]);
  load_lds16(ga + (size_t)64 * K, &As[0][2048 + lofs]);
  load_lds16(gb,                  &Bs[0][lofs]);
  if (TN == 128)
    load_lds16(gb + (size_t)64 * K, &Bs[0][2048 + lofs]);

  for (int t = 0; t < K / 32; ++t) {
    int cur = t & 1, nxt = cur ^ 1;
    __syncthreads();   // stage(t) landed (vmcnt drain); buf[nxt] free

    if (t + 1 < K / 32) {
      int ktn = (t + 1) * 32;
      load_lds16(ga + ktn,                  &As[nxt][lofs]);
      load_lds16(ga + (size_t)64 * K + ktn, &As[nxt][2048 + lofs]);
      load_lds16(gb + ktn,                  &Bs[nxt][lofs]);
      if (TN == 128)
        load_lds16(gb + (size_t)64 * K + ktn, &Bs[nxt][2048 + lofs]);
    }

    bf16x8 af[4], bfr[NI];
    #pragma unroll
    for (int i = 0; i < 4; ++i)
      af[i] = *(const bf16x8*)&As[cur][(wm + i * 16 + col) * 32 + g * 8];
    #pragma unroll
    for (int i = 0; i < NI; ++i)
      bfr[i] = *(const bf16x8*)&Bs[cur][(wn + i * 16 + col) * 32 + g * 8];
    #pragma unroll
    for (int mi = 0; mi < 4; ++mi)
      #pragma unroll
      for (int ni = 0; ni < NI; ++ni)
        acc[mi][ni] = __builtin_amdgcn_mfma_f32_16x16x32_bf16(
            af[mi], bfr[ni], acc[mi][ni], 0, 0, 0);
  }

  if (MODE == 0) {
    #pragma unroll
    for (int ni = 0; ni < NI; ++ni) {
      int n = n0 + wn + ni * 16 + col;
      float bv = bias[n];
      int t3 = n >> 10;
      int within = n & 1023;
      int h = within >> 6, d = within & 63;
      if (t3 == 2) {
        // V: PV-fragment-packed store
        #pragma unroll
        for (int mi = 0; mi < 4; ++mi) {
          int mb = m0 + wm + mi * 16 + g * 4;
          int b = mb >> 11, tok = mb & 2047;
          int kt32 = tok >> 5;
          int pair = mi & 1;
          ushort4 o;
          o.x = f2bf(acc[mi][ni][0] + bv);
          o.y = f2bf(acc[mi][ni][1] + bv);
          o.z = f2bf(acc[mi][ni][2] + bv);
          o.w = f2bf(acc[mi][ni][3] + bv);
          *(ushort4*)&vt[(((size_t)(b * NH + h) * (SEQ / 32) + kt32) * DH + d) * 32
                         + g * 8 + pair * 4] = o;
        }
      } else {
        unsigned short* dst = (t3 == 0) ? qw : kw;
        float scl = (t3 == 0) ? 0.125f : 1.0f;
        #pragma unroll
        for (int mi = 0; mi < 4; ++mi) {
          int mb = m0 + wm + mi * 16 + g * 4;
          #pragma unroll
          for (int j = 0; j < 4; ++j) {
            int m = mb + j;
            int b = m >> 11, tok = m & 2047;
            float val = (acc[mi][ni][j] + bv) * scl;
            dst[(((size_t)(b * NH + h) * SEQ + tok) << 6) + d] = f2bf(val);
          }
        }
      }
    }
  } else {
    #pragma unroll
    for (int ni = 0; ni < NI; ++ni) {
      int n = n0 + wn + ni * 16 + col;
      float bv = bias[n];
      #pragma unroll
      for (int mi = 0; mi < 4; ++mi) {
        int mb = m0 + wm + mi * 16 + g * 4;
        #pragma unroll
        for (int j = 0; j < 4; ++j)
          outF[(size_t)(mb + j) * 1024 + n] = acc[mi][ni][j] + bv;
      }
    }
  }
}

// ---------------- flash attention, LDS double-buffered DMA pipeline ----------------
// BYTE-IDENTICAL to R17 (passing, absmax 5.95e-4). Numerics frozen.
__global__ __launch_bounds__(256, 4) void attn_kernel(
    const unsigned short* __restrict__ qg,   // [B*H][SEQ][64], pre-scaled by 0.125
    const unsigned short* __restrict__ kg,   // [B*H][SEQ][64]
    const unsigned short* __restrict__ vfg,  // [B*H][SEQ/32][64][32r]
    unsigned short* __restrict__ og)         // [B][SEQ][1024] bf16
{
  __shared__ __align__(16) unsigned short lds[2][16 * 512];  // 2 x 16KB

  int tid = threadIdx.x;
  int wave = tid >> 6, lane = tid & 63;
  int col = lane & 15, g = lane >> 4;
  int bid = blockIdx.x + (blockIdx.y << 5);      // 0..1023
  int wgid = ((bid & 7) << 7) | (bid >> 3);      // XCD-chunked, bijective
  int qtile = wgid & 31;
  int bh = wgid >> 5;
  int b = bh >> 4, h = bh & 15;
  int q0 = qtile * 64 + wave * 16;

  const unsigned short* Q  = qg  + (size_t)bh * SEQ * DH;
  const unsigned short* Kp = kg  + (size_t)bh * SEQ * DH;
  const unsigned short* VF = vfg + (size_t)bh * (SEQ / 32) * DH * 32;

  const unsigned short* qr = Q + (size_t)(q0 + col) * DH + g * 8;
  bf16x8 qf0 = *(const bf16x8*)qr;
  bf16x8 qf1 = *(const bf16x8*)(qr + 32);

  // this wave's 4 staging chunks: idx 0..7 = K(ns=idx>>1, c=idx&1),
  // idx 8..15 = V(h2=(idx-8)>>2, ds=(idx-8)&3)
  int idx0 = wave * 4;

  f32x4 oacc[4] = {};
  float mrow = -1e30f, lrow = 0.0f;

  // prologue: stage tile 0 into buf 0
  #pragma unroll
  for (int i = 0; i < 4; ++i) {
    int idx = idx0 + i;
    const unsigned short* src;
    if (idx < 8) {
      int ns = idx >> 1, c = idx & 1;
      src = Kp + (size_t)(0 + ns * 16 + col) * DH + c * 32 + g * 8;
    } else {
      int vi = idx - 8, h2 = vi >> 2, ds = vi & 3;
      src = VF + (size_t)(0 + h2) * 2048 + (ds * 16 + col) * 32 + g * 8;
    }
    load_lds16(src, &lds[0][idx * 512]);
  }

  for (int t = 0; t < SEQ / 64; ++t) {
    int cur = t & 1, nxt = cur ^ 1;
    int kt = t * 64;
    __syncthreads();   // stage(t) complete (vmcnt drain) + buf[nxt] free

    // ---- issue DMA for tile t+1 into buf[nxt] ----
    if (t + 1 < SEQ / 64) {
      int ktn = kt + 64;
      #pragma unroll
      for (int i = 0; i < 4; ++i) {
        int idx = idx0 + i;
        const unsigned short* src;
        if (idx < 8) {
          int ns = idx >> 1, c = idx & 1;
          src = Kp + (size_t)(ktn + ns * 16 + col) * DH + c * 32 + g * 8;
        } else {
          int vi = idx - 8, h2 = vi >> 2, ds = vi & 3;
          src = VF + (size_t)((ktn >> 5) + h2) * 2048 + (ds * 16 + col) * 32 + g * 8;
        }
        load_lds16(src, &lds[nxt][idx * 512]);
      }
    }

    // ---- S^T = K * Q^T from LDS fragments ----
    f32x4 s[4];
    #pragma unroll
    for (int ns = 0; ns < 4; ++ns) {
      bf16x8 kf0 = *(const bf16x8*)&lds[cur][(ns * 2 + 0) * 512 + lane * 8];
      bf16x8 kf1 = *(const bf16x8*)&lds[cur][(ns * 2 + 1) * 512 + lane * 8];
      f32x4 z = {0.f, 0.f, 0.f, 0.f};
      z = __builtin_amdgcn_mfma_f32_16x16x32_bf16(kf0, qf0, z, 0, 0, 0);
      s[ns] = __builtin_amdgcn_mfma_f32_16x16x32_bf16(kf1, qf1, z, 0, 0, 0);
    }

    // ---- online softmax (per-lane; q = q0+col) ----
    float tmax = s[0][0];
    #pragma unroll
    for (int ns = 0; ns < 4; ++ns)
      #pragma unroll
      for (int jj = 0; jj < 4; ++jj)
        tmax = fmaxf(tmax, s[ns][jj]);
    tmax = fmaxf(tmax, __shfl_xor(tmax, 16));
    tmax = fmaxf(tmax, __shfl_xor(tmax, 32));
    float mn = fmaxf(mrow, tmax);
    float corr = __expf(mrow - mn);
    mrow = mn;

    float p[4][4];
    float rs = 0.0f;
    #pragma unroll
    for (int ns = 0; ns < 4; ++ns)
      #pragma unroll
      for (int jj = 0; jj < 4; ++jj) {
        float pv = __expf(s[ns][jj] - mn);
        p[ns][jj] = pv;
        rs += pv;
      }
    rs += __shfl_xor(rs, 16);
    rs += __shfl_xor(rs, 32);
    lrow = lrow * corr + rs;
    #pragma unroll
    for (int ds = 0; ds < 4; ++ds) {
      oacc[ds][0] *= corr; oacc[ds][1] *= corr;
      oacc[ds][2] *= corr; oacc[ds][3] *= corr;
    }

    // ---- pack P to bf16 fragments ----
    union U8 { bf16x8 v; unsigned int u[4]; } pf0, pf1;
    pf0.u[0] = cvt_pk_bf16(p[0][0], p[0][1]);
    pf0.u[1] = cvt_pk_bf16(p[0][2], p[0][3]);
    pf0.u[2] = cvt_pk_bf16(p[1][0], p[1][1]);
    pf0.u[3] = cvt_pk_bf16(p[1][2], p[1][3]);
    pf1.u[0] = cvt_pk_bf16(p[2][0], p[2][1]);
    pf1.u[1] = cvt_pk_bf16(p[2][2], p[2][3]);
    pf1.u[2] = cvt_pk_bf16(p[3][0], p[3][1]);
    pf1.u[3] = cvt_pk_bf16(p[3][2], p[3][3]);

    // ---- O^T += V^T * P^T (permuted-k 16x16x32), V frags from LDS ----
    #pragma unroll
    for (int ds = 0; ds < 4; ++ds) {
      bf16x8 vfA = *(const bf16x8*)&lds[cur][(8 + ds) * 512 + lane * 8];
      oacc[ds] = __builtin_amdgcn_mfma_f32_16x16x32_bf16(vfA, pf0.v, oacc[ds], 0, 0, 0);
    }
    #pragma unroll
    for (int ds = 0; ds < 4; ++ds) {
      bf16x8 vfB = *(const bf16x8*)&lds[cur][(12 + ds) * 512 + lane * 8];
      oacc[ds] = __builtin_amdgcn_mfma_f32_16x16x32_bf16(vfB, pf1.v, oacc[ds], 0, 0, 0);
    }
  }

  // ---- normalize + store: lane owns q = q0+col, d = ds*16+g*4+jj ----
  float inv = 1.0f / lrow;
  int q = q0 + col;
  unsigned short* orow = og + (size_t)(b * SEQ + q) * 1024 + h * DH;
  #pragma unroll
  for (int ds = 0; ds < 4; ++ds) {
    ushort4 o;
    o.x = f2bf(oacc[ds][0] * inv);
    o.y = f2bf(oacc[ds][1] * inv);
    o.z = f2bf(oacc[ds][2] * inv);
    o.w = f2bf(oacc[ds][3] * inv);
    *(ushort4*)&orow[ds * 16 + g * 4] = o;
  }
}

extern "C" void kernel_launch(void* const* d_in, const int* in_sizes, int n_in,
                              void* d_out, int out_size, void* d_ws, size_t ws_size,
                              hipStream_t stream) {
  const float* x      = (const float*)d_in[0];
  const float* ln_g   = (const float*)d_in[1];
  const float* ln_b   = (const float*)d_in[2];
  const float* w_qkv  = (const float*)d_in[3];
  const float* b_qkv  = (const float*)d_in[4];
  const float* w_proj = (const float*)d_in[5];
  const float* b_proj = (const float*)d_in[6];
  float* out = (float*)d_out;

  unsigned short* ws = (unsigned short*)d_ws;
  unsigned short* xn     = ws;                       // 4096*1024
  unsigned short* wqkvT  = ws + 4194304;             // 3072*1024
  unsigned short* wprojT = wqkvT + 3145728;          // 1024*1024
  unsigned short* qw     = wprojT + 1048576;         // 32*2048*64
  unsigned short* kw     = qw + 4194304;
  unsigned short* vf     = kw + 4194304;             // packed fragments
  unsigned short* ao     = xn;                       // reuse xn after QKV GEMM

  ln_cast_kernel<<<dim3(4096), dim3(256), 0, stream>>>(x, ln_g, ln_b, xn);
  transpose_cast_kernel<<<dim3(48, 16), dim3(256), 0, stream>>>(w_qkv, wqkvT, 1024, 3072);
  transpose_cast_kernel<<<dim3(16, 16), dim3(256), 0, stream>>>(w_proj, wprojT, 1024, 1024);
  gemm_kernel<0, 128><<<dim3(24, 32), dim3(256), 0, stream>>>(
      xn, wqkvT, b_qkv, nullptr, qw, kw, vf);
  attn_kernel<<<dim3(32, 32), dim3(256), 0, stream>>>(qw, kw, vf, ao);
  gemm_kernel<1, 64><<<dim3(16, 32), dim3(256), 0, stream>>>(
      ao, wprojT, b_proj, out, nullptr, nullptr, nullptr);
}

// Round 20
// 139.699 us; speedup vs baseline: 1.1166x; 1.0142x over previous
//
#include <hip/hip_runtime.h>
#include <hip/hip_bf16.h>

typedef __attribute__((ext_vector_type(8))) short bf16x8;
typedef __attribute__((ext_vector_type(4))) float f32x4;

#define SEQ  2048
#define NH   16
#define DH   64

__device__ __forceinline__ unsigned short f2bf(float f) {
  union { float f; unsigned int u; } v; v.f = f;
  unsigned int r = v.u + 0x7FFFu + ((v.u >> 16) & 1u);
  return (unsigned short)(r >> 16);
}

__device__ __forceinline__ unsigned int cvt_pk_bf16(float a, float b) {
  unsigned int r;
  asm("v_cvt_pk_bf16_f32 %0, %1, %2" : "=v"(r) : "v"(a), "v"(b));
  return r;
}

__device__ __forceinline__ void load_lds16(const void* g, void* l) {
  __builtin_amdgcn_global_load_lds(
      (const __attribute__((address_space(1))) unsigned int*)g,
      (__attribute__((address_space(3))) unsigned int*)l, 16, 0, 0);
}

// ---------------- LayerNorm + cast to bf16 (R19 verbatim) ----------------
__global__ __launch_bounds__(256) void ln_cast_kernel(
    const float* __restrict__ x, const float* __restrict__ gg,
    const float* __restrict__ bb, unsigned short* __restrict__ xn) {
  int row = blockIdx.x;                     // 0..4095
  int t = threadIdx.x;                      // 0..255, 4 floats each
  const float* xr = x + (size_t)row * 1024;
  float4 v = ((const float4*)xr)[t];
  float s  = v.x + v.y + v.z + v.w;
  float ss = v.x*v.x + v.y*v.y + v.z*v.z + v.w*v.w;
  #pragma unroll
  for (int m = 1; m < 64; m <<= 1) {
    s  += __shfl_xor(s, m);
    ss += __shfl_xor(ss, m);
  }
  __shared__ float red[8];
  int wave = t >> 6;
  if ((t & 63) == 0) { red[wave] = s; red[wave + 4] = ss; }
  __syncthreads();
  s  = red[0] + red[1] + red[2] + red[3];
  ss = red[4] + red[5] + red[6] + red[7];
  float mu  = s * (1.0f / 1024.0f);
  float var = ss * (1.0f / 1024.0f) - mu * mu;
  float rstd = rsqrtf(var + 1e-5f);
  float4 g4 = ((const float4*)gg)[t];
  float4 b4 = ((const float4*)bb)[t];
  ushort4 o;
  o.x = f2bf((v.x - mu) * rstd * g4.x + b4.x);
  o.y = f2bf((v.y - mu) * rstd * g4.y + b4.y);
  o.z = f2bf((v.z - mu) * rstd * g4.z + b4.z);
  o.w = f2bf((v.w - mu) * rstd * g4.w + b4.w);
  ((ushort4*)(xn + (size_t)row * 1024))[t] = o;
}

// ------- fused transpose + cast for BOTH weights (single launch) -------
// Per-element math is contraction-free (load -> f2bf -> store), so output is
// bit-identical to the two separate R19 launches; only launch count changes.
// grid 1024: bid < 768 -> w_qkv tile (48 x 16), else w_proj tile (16 x 16).
__global__ __launch_bounds__(256) void transpose_cast2_kernel(
    const float* __restrict__ wq, unsigned short* __restrict__ wqt,
    const float* __restrict__ wp, unsigned short* __restrict__ wpt) {
  __shared__ unsigned short tile[64][68];
  int bidx = blockIdx.x;
  const float* w;
  unsigned short* wt;
  int K = 1024, Nn, tx, ty;
  if (bidx < 768) {
    w = wq; wt = wqt; Nn = 3072;
    tx = bidx % 48; ty = bidx / 48;
  } else {
    int i = bidx - 768;
    w = wp; wt = wpt; Nn = 1024;
    tx = i % 16; ty = i / 16;
  }
  int k0 = ty * 64;
  int n0 = tx * 64;
  int t = threadIdx.x;
  int tr = t >> 4;            // 0..15
  int tc = (t & 15) * 4;      // 0..60
  #pragma unroll
  for (int it = 0; it < 4; ++it) {
    int r = tr + it * 16;
    float4 v = *(const float4*)(w + (size_t)(k0 + r) * Nn + n0 + tc);
    tile[r][tc + 0] = f2bf(v.x);
    tile[r][tc + 1] = f2bf(v.y);
    tile[r][tc + 2] = f2bf(v.z);
    tile[r][tc + 3] = f2bf(v.w);
  }
  __syncthreads();
  #pragma unroll
  for (int it = 0; it < 4; ++it) {
    int nr = tr + it * 16;
    ushort4 o;
    o.x = tile[tc + 0][nr];
    o.y = tile[tc + 1][nr];
    o.z = tile[tc + 2][nr];
    o.w = tile[tc + 3][nr];
    *(ushort4*)(wt + (size_t)(n0 + nr) * K + k0 + tc) = o;
  }
}

// ---------------- GEMM: C[M x TN-tile] = A[M][1024] * Bt[Nn][1024]^T + bias --------
// R19 verbatim: gemm<0> TN=128 (3 blocks/CU, fat tile keeps A-side L2 traffic
// low), gemm<1> TN=64 (2 blocks/CU hides the barrier drain; R18 proved TN=64
// on gemm<0> regresses).
template<int MODE, int TN>
__global__ __launch_bounds__(256) void gemm_kernel(
    const unsigned short* __restrict__ A,
    const unsigned short* __restrict__ Bt,
    const float* __restrict__ bias,
    float* __restrict__ outF,
    unsigned short* __restrict__ qw,
    unsigned short* __restrict__ kw,
    unsigned short* __restrict__ vt)
{
  constexpr int K = 1024;
  constexpr int NI = TN / 32;            // B-frag repeats per wave (4 or 2)
  __shared__ __align__(16) unsigned short As[2][128 * 32];
  __shared__ __align__(16) unsigned short Bs[2][TN * 32];
  int tid = threadIdx.x;
  int wave = tid >> 6, lane = tid & 63;
  int col = lane & 15, g = lane >> 4;

  // XCD-chunked swizzle (bijective since nwg % 8 == 0)
  int nwg = gridDim.x * gridDim.y;
  int bid = blockIdx.y * gridDim.x + blockIdx.x;
  int wg = (bid & 7) * (nwg >> 3) + (bid >> 3);
  int n0 = (wg % gridDim.x) * TN;
  int m0 = (wg / gridDim.x) * 128;

  int wm = (wave >> 1) * 64, wn = (wave & 1) * (TN / 2);
  int r0 = tid >> 2, ch = (tid & 3) * 8;

  f32x4 acc[4][NI] = {};

  const unsigned short* ga = A  + (size_t)(m0 + r0) * K + ch;
  const unsigned short* gb = Bt + (size_t)(n0 + r0) * K + ch;
  int lofs = wave * 512;

  // prologue: stage K-step 0 into buffer 0
  load_lds16(ga,                  &As[0][lofs]);
  load_lds16(ga + (size_t)64 * K, &As[0][2048 + lofs]);
  load_lds16(gb,                  &Bs[0][lofs]);
  if (TN == 128)
    load_lds16(gb + (size_t)64 * K, &Bs[0][2048 + lofs]);

  for (int t = 0; t < K / 32; ++t) {
    int cur = t & 1, nxt = cur ^ 1;
    __syncthreads();   // stage(t) landed (vmcnt drain); buf[nxt] free

    if (t + 1 < K / 32) {
      int ktn = (t + 1) * 32;
      load_lds16(ga + ktn,                  &As[nxt][lofs]);
      load_lds16(ga + (size_t)64 * K + ktn, &As[nxt][2048 + lofs]);
      load_lds16(gb + ktn,                  &Bs[nxt][lofs]);
      if (TN == 128)
        load_lds16(gb + (size_t)64 * K + ktn, &Bs[nxt][2048 + lofs]);
    }

    bf16x8 af[4], bfr[NI];
    #pragma unroll
    for (int i = 0; i < 4; ++i)
      af[i] = *(const bf16x8*)&As[cur][(wm + i * 16 + col) * 32 + g * 8];
    #pragma unroll
    for (int i = 0; i < NI; ++i)
      bfr[i] = *(const bf16x8*)&Bs[cur][(wn + i * 16 + col) * 32 + g * 8];
    #pragma unroll
    for (int mi = 0; mi < 4; ++mi)
      #pragma unroll
      for (int ni = 0; ni < NI; ++ni)
        acc[mi][ni] = __builtin_amdgcn_mfma_f32_16x16x32_bf16(
            af[mi], bfr[ni], acc[mi][ni], 0, 0, 0);
  }

  if (MODE == 0) {
    #pragma unroll
    for (int ni = 0; ni < NI; ++ni) {
      int n = n0 + wn + ni * 16 + col;
      float bv = bias[n];
      int t3 = n >> 10;
      int within = n & 1023;
      int h = within >> 6, d = within & 63;
      if (t3 == 2) {
        // V: PV-fragment-packed store
        #pragma unroll
        for (int mi = 0; mi < 4; ++mi) {
          int mb = m0 + wm + mi * 16 + g * 4;
          int b = mb >> 11, tok = mb & 2047;
          int kt32 = tok >> 5;
          int pair = mi & 1;
          ushort4 o;
          o.x = f2bf(acc[mi][ni][0] + bv);
          o.y = f2bf(acc[mi][ni][1] + bv);
          o.z = f2bf(acc[mi][ni][2] + bv);
          o.w = f2bf(acc[mi][ni][3] + bv);
          *(ushort4*)&vt[(((size_t)(b * NH + h) * (SEQ / 32) + kt32) * DH + d) * 32
                         + g * 8 + pair * 4] = o;
        }
      } else {
        unsigned short* dst = (t3 == 0) ? qw : kw;
        float scl = (t3 == 0) ? 0.125f : 1.0f;
        #pragma unroll
        for (int mi = 0; mi < 4; ++mi) {
          int mb = m0 + wm + mi * 16 + g * 4;
          #pragma unroll
          for (int j = 0; j < 4; ++j) {
            int m = mb + j;
            int b = m >> 11, tok = m & 2047;
            float val = (acc[mi][ni][j] + bv) * scl;
            dst[(((size_t)(b * NH + h) * SEQ + tok) << 6) + d] = f2bf(val);
          }
        }
      }
    }
  } else {
    #pragma unroll
    for (int ni = 0; ni < NI; ++ni) {
      int n = n0 + wn + ni * 16 + col;
      float bv = bias[n];
      #pragma unroll
      for (int mi = 0; mi < 4; ++mi) {
        int mb = m0 + wm + mi * 16 + g * 4;
        #pragma unroll
        for (int j = 0; j < 4; ++j)
          outF[(size_t)(mb + j) * 1024 + n] = acc[mi][ni][j] + bv;
      }
    }
  }
}

// ---------------- flash attention, LDS double-buffered DMA pipeline ----------------
// BYTE-IDENTICAL to R19 (passing). Numerics frozen.
__global__ __launch_bounds__(256, 4) void attn_kernel(
    const unsigned short* __restrict__ qg,   // [B*H][SEQ][64], pre-scaled by 0.125
    const unsigned short* __restrict__ kg,   // [B*H][SEQ][64]
    const unsigned short* __restrict__ vfg,  // [B*H][SEQ/32][64][32r]
    unsigned short* __restrict__ og)         // [B][SEQ][1024] bf16
{
  __shared__ __align__(16) unsigned short lds[2][16 * 512];  // 2 x 16KB

  int tid = threadIdx.x;
  int wave = tid >> 6, lane = tid & 63;
  int col = lane & 15, g = lane >> 4;
  int bid = blockIdx.x + (blockIdx.y << 5);      // 0..1023
  int wgid = ((bid & 7) << 7) | (bid >> 3);      // XCD-chunked, bijective
  int qtile = wgid & 31;
  int bh = wgid >> 5;
  int b = bh >> 4, h = bh & 15;
  int q0 = qtile * 64 + wave * 16;

  const unsigned short* Q  = qg  + (size_t)bh * SEQ * DH;
  const unsigned short* Kp = kg  + (size_t)bh * SEQ * DH;
  const unsigned short* VF = vfg + (size_t)bh * (SEQ / 32) * DH * 32;

  const unsigned short* qr = Q + (size_t)(q0 + col) * DH + g * 8;
  bf16x8 qf0 = *(const bf16x8*)qr;
  bf16x8 qf1 = *(const bf16x8*)(qr + 32);

  // this wave's 4 staging chunks: idx 0..7 = K(ns=idx>>1, c=idx&1),
  // idx 8..15 = V(h2=(idx-8)>>2, ds=(idx-8)&3)
  int idx0 = wave * 4;

  f32x4 oacc[4] = {};
  float mrow = -1e30f, lrow = 0.0f;

  // prologue: stage tile 0 into buf 0
  #pragma unroll
  for (int i = 0; i < 4; ++i) {
    int idx = idx0 + i;
    const unsigned short* src;
    if (idx < 8) {
      int ns = idx >> 1, c = idx & 1;
      src = Kp + (size_t)(0 + ns * 16 + col) * DH + c * 32 + g * 8;
    } else {
      int vi = idx - 8, h2 = vi >> 2, ds = vi & 3;
      src = VF + (size_t)(0 + h2) * 2048 + (ds * 16 + col) * 32 + g * 8;
    }
    load_lds16(src, &lds[0][idx * 512]);
  }

  for (int t = 0; t < SEQ / 64; ++t) {
    int cur = t & 1, nxt = cur ^ 1;
    int kt = t * 64;
    __syncthreads();   // stage(t) complete (vmcnt drain) + buf[nxt] free

    // ---- issue DMA for tile t+1 into buf[nxt] ----
    if (t + 1 < SEQ / 64) {
      int ktn = kt + 64;
      #pragma unroll
      for (int i = 0; i < 4; ++i) {
        int idx = idx0 + i;
        const unsigned short* src;
        if (idx < 8) {
          int ns = idx >> 1, c = idx & 1;
          src = Kp + (size_t)(ktn + ns * 16 + col) * DH + c * 32 + g * 8;
        } else {
          int vi = idx - 8, h2 = vi >> 2, ds = vi & 3;
          src = VF + (size_t)((ktn >> 5) + h2) * 2048 + (ds * 16 + col) * 32 + g * 8;
        }
        load_lds16(src, &lds[nxt][idx * 512]);
      }
    }

    // ---- S^T = K * Q^T from LDS fragments ----
    f32x4 s[4];
    #pragma unroll
    for (int ns = 0; ns < 4; ++ns) {
      bf16x8 kf0 = *(const bf16x8*)&lds[cur][(ns * 2 + 0) * 512 + lane * 8];
      bf16x8 kf1 = *(const bf16x8*)&lds[cur][(ns * 2 + 1) * 512 + lane * 8];
      f32x4 z = {0.f, 0.f, 0.f, 0.f};
      z = __builtin_amdgcn_mfma_f32_16x16x32_bf16(kf0, qf0, z, 0, 0, 0);
      s[ns] = __builtin_amdgcn_mfma_f32_16x16x32_bf16(kf1, qf1, z, 0, 0, 0);
    }

    // ---- online softmax (per-lane; q = q0+col) ----
    float tmax = s[0][0];
    #pragma unroll
    for (int ns = 0; ns < 4; ++ns)
      #pragma unroll
      for (int jj = 0; jj < 4; ++jj)
        tmax = fmaxf(tmax, s[ns][jj]);
    tmax = fmaxf(tmax, __shfl_xor(tmax, 16));
    tmax = fmaxf(tmax, __shfl_xor(tmax, 32));
    float mn = fmaxf(mrow, tmax);
    float corr = __expf(mrow - mn);
    mrow = mn;

    float p[4][4];
    float rs = 0.0f;
    #pragma unroll
    for (int ns = 0; ns < 4; ++ns)
      #pragma unroll
      for (int jj = 0; jj < 4; ++jj) {
        float pv = __expf(s[ns][jj] - mn);
        p[ns][jj] = pv;
        rs += pv;
      }
    rs += __shfl_xor(rs, 16);
    rs += __shfl_xor(rs, 32);
    lrow = lrow * corr + rs;
    #pragma unroll
    for (int ds = 0; ds < 4; ++ds) {
      oacc[ds][0] *= corr; oacc[ds][1] *= corr;
      oacc[ds][2] *= corr; oacc[ds][3] *= corr;
    }

    // ---- pack P to bf16 fragments ----
    union U8 { bf16x8 v; unsigned int u[4]; } pf0, pf1;
    pf0.u[0] = cvt_pk_bf16(p[0][0], p[0][1]);
    pf0.u[1] = cvt_pk_bf16(p[0][2], p[0][3]);
    pf0.u[2] = cvt_pk_bf16(p[1][0], p[1][1]);
    pf0.u[3] = cvt_pk_bf16(p[1][2], p[1][3]);
    pf1.u[0] = cvt_pk_bf16(p[2][0], p[2][1]);
    pf1.u[1] = cvt_pk_bf16(p[2][2], p[2][3]);
    pf1.u[2] = cvt_pk_bf16(p[3][0], p[3][1]);
    pf1.u[3] = cvt_pk_bf16(p[3][2], p[3][3]);

    // ---- O^T += V^T * P^T (permuted-k 16x16x32), V frags from LDS ----
    #pragma unroll
    for (int ds = 0; ds < 4; ++ds) {
      bf16x8 vfA = *(const bf16x8*)&lds[cur][(8 + ds) * 512 + lane * 8];
      oacc[ds] = __builtin_amdgcn_mfma_f32_16x16x32_bf16(vfA, pf0.v, oacc[ds], 0, 0, 0);
    }
    #pragma unroll
    for (int ds = 0; ds < 4; ++ds) {
      bf16x8 vfB = *(const bf16x8*)&lds[cur][(12 + ds) * 512 + lane * 8];
      oacc[ds] = __builtin_amdgcn_mfma_f32_16x16x32_bf16(vfB, pf1.v, oacc[ds], 0, 0, 0);
    }
  }

  // ---- normalize + store: lane owns q = q0+col, d = ds*16+g*4+jj ----
  float inv = 1.0f / lrow;
  int q = q0 + col;
  unsigned short* orow = og + (size_t)(b * SEQ + q) * 1024 + h * DH;
  #pragma unroll
  for (int ds = 0; ds < 4; ++ds) {
    ushort4 o;
    o.x = f2bf(oacc[ds][0] * inv);
    o.y = f2bf(oacc[ds][1] * inv);
    o.z = f2bf(oacc[ds][2] * inv);
    o.w = f2bf(oacc[ds][3] * inv);
    *(ushort4*)&orow[ds * 16 + g * 4] = o;
  }
}

extern "C" void kernel_launch(void* const* d_in, const int* in_sizes, int n_in,
                              void* d_out, int out_size, void* d_ws, size_t ws_size,
                              hipStream_t stream) {
  const float* x      = (const float*)d_in[0];
  const float* ln_g   = (const float*)d_in[1];
  const float* ln_b   = (const float*)d_in[2];
  const float* w_qkv  = (const float*)d_in[3];
  const float* b_qkv  = (const float*)d_in[4];
  const float* w_proj = (const float*)d_in[5];
  const float* b_proj = (const float*)d_in[6];
  float* out = (float*)d_out;

  unsigned short* ws = (unsigned short*)d_ws;
  unsigned short* xn     = ws;                       // 4096*1024
  unsigned short* wqkvT  = ws + 4194304;             // 3072*1024
  unsigned short* wprojT = wqkvT + 3145728;          // 1024*1024
  unsigned short* qw     = wprojT + 1048576;         // 32*2048*64
  unsigned short* kw     = qw + 4194304;
  unsigned short* vf     = kw + 4194304;             // packed fragments
  unsigned short* ao     = xn;                       // reuse xn after QKV GEMM

  ln_cast_kernel<<<dim3(4096), dim3(256), 0, stream>>>(x, ln_g, ln_b, xn);
  transpose_cast2_kernel<<<dim3(1024), dim3(256), 0, stream>>>(
      w_qkv, wqkvT, w_proj, wprojT);
  gemm_kernel<0, 128><<<dim3(24, 32), dim3(256), 0, stream>>>(
      xn, wqkvT, b_qkv, nullptr, qw, kw, vf);
  attn_kernel<<<dim3(32, 32), dim3(256), 0, stream>>>(qw, kw, vf, ao);
  gemm_kernel<1, 64><<<dim3(16, 32), dim3(256), 0, stream>>>(
      ao, wprojT, b_proj, out, nullptr, nullptr, nullptr);
}